// Round 10
// baseline (224.115 us; speedup 1.0000x reference)
//
#include <hip/hip_runtime.h>
#include <hip/hip_bf16.h>

// ---------------------------------------------------------------------------
// BidirectionalGINConv: out = relu(0.5*(gin(ei) + gin(rei)))
// Restructured (linearity of segsum; shared w2):
//   z = x@w1^T                 (bf16 MFMA GEMM, epilogue packs z to bf16)
//   adjacency: partition into 256-node bucket slabs -> in-LDS counting sort CSR
//   agg_i = segsum(z[src_i])   (column-quartered XCD-affine gather)
//   s = 0.5*(relu(z+b1+agg1)+relu(z+b1+agg2))  (fused in gather, bf16 out)
//   out = relu(s@w2^T + b2)    (bf16 MFMA GEMM, f32 epilogue)
// NOTES:
//   r7: LDS f32 atomicAdd = CAS retry loop on gfx950 -> never on critical path.
//   r8: prep_k OOB clobbered wbf2 -> 32 conversion blocks + 1 cursor block.
//   r9: gather was L2-miss bound (z=12.8MB > 4MB/XCD L2, FETCH 151MB).
//       Fix: quarter the columns (64B line/edge/quarter) + tie quarter to
//       blockIdx%8 so each XCD's z working set is 3.2MB (L2-resident).
// ---------------------------------------------------------------------------

#define C_BKT    196     // coarse buckets: b = dst>>8 (256 nodes each)
#define SLAB_CAP 4608    // per-bucket slab capacity; mean 4096 -> +8 sigma
#define CHUNK    4096    // edges per partition block

typedef __attribute__((ext_vector_type(8))) short short8;
typedef __attribute__((ext_vector_type(4))) float f32x4;

__device__ inline unsigned packbf2(float f0, float f1) {   // RNE bf16 pair
    unsigned u0 = __float_as_uint(f0), u1 = __float_as_uint(f1);
    u0 = (u0 + 0x7fffu + ((u0 >> 16) & 1u)) >> 16;
    u1 = (u1 + 0x7fffu + ((u1 >> 16) & 1u)) >> 16;
    return u0 | (u1 << 16);
}

#define BFLO(p) __uint_as_float((p) << 16)
#define BFHI(p) __uint_as_float((p) & 0xffff0000u)

// prep: convert w1,w2 (8192 float2 pairs each) to bf16-packed uints + cursors.
__global__ void prep_k(const float* __restrict__ w1, const float* __restrict__ w2,
                       unsigned* __restrict__ wbf1, unsigned* __restrict__ wbf2,
                       int* __restrict__ gcur1, int* __restrict__ gcur2) {
    int b = blockIdx.x, t = threadIdx.x;
    if (b == 32) {
        if (t < C_BKT) { gcur1[t] = t * SLAB_CAP; gcur2[t] = t * SLAB_CAP; }
        return;
    }
    int p = b * 256 + t;                 // pair index 0..8191
    const float2 v1 = ((const float2*)w1)[p];
    const float2 v2 = ((const float2*)w2)[p];
    wbf1[p] = packbf2(v1.x, v1.y);
    wbf2[p] = packbf2(v2.x, v2.y);
}

// Phase A: partition both edge lists into coarse slabs with DENSE writes.
// Packed record: (dst & 255) << 16 | src   (src < 65536).
__global__ __launch_bounds__(256) void partition_k(
        const int* __restrict__ src1, const int* __restrict__ dst1,
        const int* __restrict__ src2, const int* __restrict__ dst2,
        unsigned* __restrict__ slab1, unsigned* __restrict__ slab2,
        int* __restrict__ gcur1, int* __restrict__ gcur2, int E, int NB) {
    __shared__ unsigned sorted[CHUNK];
    __shared__ unsigned gpos[CHUNK];
    __shared__ int hist[256], loff[256], goff[256], cur[256];

    int t = threadIdx.x;
    int dir = (blockIdx.x >= NB) ? 1 : 0;
    int cb = dir ? (blockIdx.x - NB) : blockIdx.x;
    const int* srcp = dir ? src2 : src1;
    const int* dstp = dir ? dst2 : dst1;
    unsigned* slab = dir ? slab2 : slab1;
    int* gcur = dir ? gcur2 : gcur1;

    hist[t] = 0;
    __syncthreads();

    unsigned vv[16]; int bb[16];
    int base = cb * CHUNK;
    #pragma unroll
    for (int k = 0; k < 16; ++k) {
        int i = base + k * 256 + t;
        if (i < E) {
            int s = srcp[i], d = dstp[i];
            bb[k] = d >> 8;
            vv[k] = ((unsigned)(d & 255) << 16) | (unsigned)s;
            atomicAdd(&hist[bb[k]], 1);
        } else bb[k] = -1;
    }
    __syncthreads();

    int c = hist[t];
    if (t < C_BKT && c > 0) goff[t] = atomicAdd(&gcur[t], c);
    for (int d = 1; d < 256; d <<= 1) {
        int v = (t >= d) ? hist[t - d] : 0;
        __syncthreads();
        hist[t] += v;
        __syncthreads();
    }
    loff[t] = hist[t] - c;
    cur[t] = 0;
    __syncthreads();
    int nv = hist[255];

    #pragma unroll
    for (int k = 0; k < 16; ++k) {
        if (bb[k] >= 0) {
            int b = bb[k];
            int r = atomicAdd(&cur[b], 1);
            int p = loff[b] + r;
            sorted[p] = vv[k];
            int gp = goff[b] + r;
            gpos[p] = (gp < (b + 1) * SLAB_CAP) ? (unsigned)gp : 0xFFFFFFFFu;
        }
    }
    __syncthreads();

    for (int j = t; j < nv; j += 256) {
        unsigned gp = gpos[j];
        if (gp != 0xFFFFFFFFu) slab[gp] = sorted[j];
    }
}

// Phase B: per (bucket, dir): counting-sort slab by node in LDS, emit exact CSR.
__global__ __launch_bounds__(256) void csr_k(
        const unsigned* __restrict__ slab1, const unsigned* __restrict__ slab2,
        const int* __restrict__ gcur1, const int* __restrict__ gcur2,
        unsigned short* __restrict__ list1, unsigned short* __restrict__ list2,
        unsigned* __restrict__ goff1, unsigned* __restrict__ goff2,
        unsigned short* __restrict__ gcnt1, unsigned short* __restrict__ gcnt2,
        int N) {
    __shared__ unsigned short srt[SLAB_CAP];
    __shared__ int cnt[256], loff[256], cur[256];

    int t = threadIdx.x;
    int dir = (blockIdx.x >= C_BKT) ? 1 : 0;
    int b = dir ? (blockIdx.x - C_BKT) : blockIdx.x;
    const unsigned* sl = (dir ? slab2 : slab1) + (size_t)b * SLAB_CAP;
    unsigned short* lst = dir ? list2 : list1;
    unsigned* goffN = dir ? goff2 : goff1;
    unsigned short* gcntN = dir ? gcnt2 : gcnt1;
    int nv = (dir ? gcur2 : gcur1)[b] - b * SLAB_CAP;
    if (nv > SLAB_CAP) nv = SLAB_CAP;

    cnt[t] = 0;
    __syncthreads();
    for (int j = t; j < nv; j += 256) atomicAdd(&cnt[sl[j] >> 16], 1);
    __syncthreads();

    int c = cnt[t];
    for (int d = 1; d < 256; d <<= 1) {
        int v = (t >= d) ? cnt[t - d] : 0;
        __syncthreads();
        cnt[t] += v;
        __syncthreads();
    }
    loff[t] = cnt[t] - c;
    cur[t] = 0;
    int node = b * 256 + t;
    if (node < N) {
        goffN[node] = (unsigned)(b * SLAB_CAP + loff[t]);
        gcntN[node] = (unsigned short)c;
    }
    __syncthreads();

    for (int j = t; j < nv; j += 256) {
        unsigned v = sl[j];
        int n = v >> 16;
        int r = atomicAdd(&cur[n], 1);
        srt[loff[n] + r] = (unsigned short)(v & 0xffffu);
    }
    __syncthreads();
    for (int j = t; j < nv; j += 256)
        lst[(size_t)b * SLAB_CAP + j] = srt[j];
}

// ---------------- MFMA GEMMs (16x16x32 bf16) ----------------
// Block = 256 threads = 4 waves; wave w -> rows [blk*64 + w*16, +16).
// A/B share the same per-lane k-mapping (k-permutation invariant).
// C/D: col=lane&15, row=(lane>>4)*4+reg  [m89-verified].

// GEMM1: A = x (f32, convert on load), out = z packed bf16 (LDS-staged).
__global__ __launch_bounds__(256) void gemm1_mfma_k(
        const float* __restrict__ A, const unsigned* __restrict__ wbf,
        unsigned* __restrict__ zb, int M) {
    __shared__ float cst[64 * 129];
    int t = threadIdx.x;
    int lane = t & 63, wv = t >> 6;
    int l16 = lane & 15, kg = lane >> 4;
    int rowBase = blockIdx.x * 64 + wv * 16;
    int ar = rowBase + l16; if (ar >= M) ar = M - 1;

    f32x4 acc[8];
    #pragma unroll
    for (int ct = 0; ct < 8; ++ct) acc[ct] = (f32x4){0.f, 0.f, 0.f, 0.f};

    const float4* arow = (const float4*)(A + (size_t)ar * 128);
    #pragma unroll
    for (int kt = 0; kt < 4; ++kt) {
        float4 v0 = arow[kt * 8 + kg * 2];
        float4 v1 = arow[kt * 8 + kg * 2 + 1];
        uint4 au = make_uint4(packbf2(v0.x, v0.y), packbf2(v0.z, v0.w),
                              packbf2(v1.x, v1.y), packbf2(v1.z, v1.w));
        short8 a = *(short8*)&au;
        #pragma unroll
        for (int ct = 0; ct < 8; ++ct) {
            uint4 bu = *(const uint4*)(wbf + (size_t)(ct * 16 + l16) * 64 + kt * 16 + kg * 4);
            short8 b = *(short8*)&bu;
            acc[ct] = __builtin_amdgcn_mfma_f32_16x16x32_bf16(a, b, acc[ct], 0, 0, 0);
        }
    }

    #pragma unroll
    for (int ct = 0; ct < 8; ++ct)
        #pragma unroll
        for (int r = 0; r < 4; ++r)
            cst[(wv * 16 + kg * 4 + r) * 129 + ct * 16 + l16] = acc[ct][r];
    __syncthreads();

    int row = t & 63, q = t >> 6;
    int grow = blockIdx.x * 64 + row;
    if (grow < M) {
        const float* src = cst + row * 129 + q * 32;
        unsigned pk[16];
        #pragma unroll
        for (int i = 0; i < 16; ++i) pk[i] = packbf2(src[2 * i], src[2 * i + 1]);
        uint4* dst = (uint4*)(zb + (size_t)grow * 64 + q * 16);
        #pragma unroll
        for (int qq = 0; qq < 4; ++qq)
            dst[qq] = make_uint4(pk[4 * qq], pk[4 * qq + 1], pk[4 * qq + 2], pk[4 * qq + 3]);
    }
}

// GEMM2: A = s (bf16), out = relu(A@W^T + b2) f32. Direct stores.
__global__ __launch_bounds__(256) void gemm2_mfma_k(
        const unsigned* __restrict__ sB, const unsigned* __restrict__ wbf,
        const float* __restrict__ bias, float* __restrict__ O, int M) {
    int t = threadIdx.x;
    int lane = t & 63, wv = t >> 6;
    int l16 = lane & 15, kg = lane >> 4;
    int rowBase = blockIdx.x * 64 + wv * 16;
    int ar = rowBase + l16; if (ar >= M) ar = M - 1;

    f32x4 acc[8];
    #pragma unroll
    for (int ct = 0; ct < 8; ++ct) acc[ct] = (f32x4){0.f, 0.f, 0.f, 0.f};

    #pragma unroll
    for (int kt = 0; kt < 4; ++kt) {
        uint4 au = *(const uint4*)(sB + (size_t)ar * 64 + kt * 16 + kg * 4);
        short8 a = *(short8*)&au;
        #pragma unroll
        for (int ct = 0; ct < 8; ++ct) {
            uint4 bu = *(const uint4*)(wbf + (size_t)(ct * 16 + l16) * 64 + kt * 16 + kg * 4);
            short8 b = *(short8*)&bu;
            acc[ct] = __builtin_amdgcn_mfma_f32_16x16x32_bf16(a, b, acc[ct], 0, 0, 0);
        }
    }

    #pragma unroll
    for (int ct = 0; ct < 8; ++ct) {
        int col = ct * 16 + l16;
        float bv = bias[col];
        #pragma unroll
        for (int r = 0; r < 4; ++r) {
            int grow = rowBase + kg * 4 + r;
            if (grow < M)
                O[(size_t)grow * 128 + col] = fmaxf(acc[ct][r] + bv, 0.f);
        }
    }
}

// ---------------- column-quartered XCD-affine gather ----------------
// quarter q = (blockIdx%8)>>1  -> with round-robin block->XCD dispatch, each
// XCD pair serves one 32-col quarter => z working set 3.2MB < 4MB L2.
// Wave = 1 node: 4 edge-slots x 16 lanes; each slot reads one 64B z line
// per edge. Main loop: 16 edges (4 loads/lane in flight). Cross-slot
// reduction via shfl_xor; lanes 0-15 write the 64B s quarter.
__global__ __launch_bounds__(256) void gather_fuse_k(
        const unsigned* __restrict__ zb,
        const unsigned* __restrict__ goff1, const unsigned short* __restrict__ gcnt1,
        const unsigned short* __restrict__ list1,
        const unsigned* __restrict__ goff2, const unsigned short* __restrict__ gcnt2,
        const unsigned short* __restrict__ list2,
        const float* __restrict__ b1, unsigned* __restrict__ sOut, int N) {
    int bid = blockIdx.x;
    int q  = (bid & 7) >> 1;                 // column quarter (XCD-affine)
    int ng = (bid >> 3) * 2 + (bid & 1);     // node group of 4
    int t = threadIdx.x;
    int wv = t >> 6, lane = t & 63;
    int l16 = lane & 15, es = lane >> 4;     // edge slot 0..3
    int g = ng * 4 + wv;
    if (g >= N) return;
    int zq = q * 16 + l16;                   // uint offset within 64-uint row

    float a1x = 0.f, a1y = 0.f, a2x = 0.f, a2y = 0.f;

    #pragma unroll
    for (int d = 0; d < 2; ++d) {
        const unsigned* goff = d ? goff2 : goff1;
        const unsigned short* gcnt = d ? gcnt2 : gcnt1;
        const unsigned short* list = d ? list2 : list1;
        float ax = 0.f, ay = 0.f;

        int o = (int)goff[g], c = (int)gcnt[g], i = 0;
        for (; i + 16 <= c; i += 16) {
            unsigned i0 = list[o + i + es];
            unsigned i1 = list[o + i + 4 + es];
            unsigned i2 = list[o + i + 8 + es];
            unsigned i3 = list[o + i + 12 + es];
            unsigned p0 = zb[(size_t)i0 * 64 + zq];
            unsigned p1 = zb[(size_t)i1 * 64 + zq];
            unsigned p2 = zb[(size_t)i2 * 64 + zq];
            unsigned p3 = zb[(size_t)i3 * 64 + zq];
            ax += (BFLO(p0) + BFLO(p1)) + (BFLO(p2) + BFLO(p3));
            ay += (BFHI(p0) + BFHI(p1)) + (BFHI(p2) + BFHI(p3));
        }
        for (; i < c; i += 4) {
            int e = i + es;
            bool val = (e < c);
            unsigned idx = val ? list[o + e] : (unsigned)g;
            unsigned p = zb[(size_t)idx * 64 + zq];
            float m = val ? 1.f : 0.f;
            ax += m * BFLO(p);
            ay += m * BFHI(p);
        }
        if (d) { a2x = ax; a2y = ay; } else { a1x = ax; a1y = ay; }
    }

    // reduce across the 4 edge slots (lanes l16, l16+16, l16+32, l16+48)
    a1x += __shfl_xor(a1x, 16); a1x += __shfl_xor(a1x, 32);
    a1y += __shfl_xor(a1y, 16); a1y += __shfl_xor(a1y, 32);
    a2x += __shfl_xor(a2x, 16); a2x += __shfl_xor(a2x, 32);
    a2y += __shfl_xor(a2y, 16); a2y += __shfl_xor(a2y, 32);

    if (es == 0) {
        unsigned pz = zb[(size_t)g * 64 + zq];
        float2 bb = ((const float2*)b1)[zq];
        float bx = BFLO(pz) + bb.x, by = BFHI(pz) + bb.y;
        float ox = 0.5f * (fmaxf(bx + a1x, 0.f) + fmaxf(bx + a2x, 0.f));
        float oy = 0.5f * (fmaxf(by + a1y, 0.f) + fmaxf(by + a2y, 0.f));
        sOut[(size_t)g * 64 + zq] = packbf2(ox, oy);
    }
}

extern "C" void kernel_launch(void* const* d_in, const int* in_sizes, int n_in,
                              void* d_out, int out_size, void* d_ws, size_t ws_size,
                              hipStream_t stream) {
    const float* x   = (const float*)d_in[0];
    const int*   ei  = (const int*)d_in[1];
    const int*   rei = (const int*)d_in[2];
    const float* w1  = (const float*)d_in[3];
    const float* b1  = (const float*)d_in[4];
    const float* w2  = (const float*)d_in[5];
    const float* b2  = (const float*)d_in[6];
    float* out = (float*)d_out;

    const int N = in_sizes[0] / 128;      // 50000
    const int E = in_sizes[1] / 2;        // 800000
    const size_t ND = (size_t)N * 128;
    const size_t SL = (size_t)C_BKT * SLAB_CAP;   // 903168

    // ws layout (~38 MB)
    unsigned* zb    = (unsigned*)d_ws;            // N*64  (bf16 z, 12.8 MB)
    unsigned* sb    = zb + ND / 2;                // N*64  (bf16 s, 12.8 MB)
    unsigned* wbf1  = sb + ND / 2;                // 8192  (bf16 w1, 32 KB)
    unsigned* wbf2  = wbf1 + 8192;                // 8192
    unsigned* slab1 = wbf2 + 8192;                // SL
    unsigned* slab2 = slab1 + SL;                 // SL
    unsigned* goff1 = slab2 + SL;                 // N
    unsigned* goff2 = goff1 + N;                  // N
    int*      gcur1 = (int*)(goff2 + N);          // C_BKT
    int*      gcur2 = gcur1 + C_BKT;              // C_BKT
    unsigned short* gcnt1 = (unsigned short*)(gcur2 + C_BKT);  // N
    unsigned short* gcnt2 = gcnt1 + N;            // N
    unsigned short* list1 = gcnt2 + N;            // SL
    unsigned short* list2 = list1 + SL;           // SL

    const int* src1 = ei,  *dst1 = ei + E;
    const int* src2 = rei, *dst2 = rei + E;

    // 1. weight bf16 convert (8192 pairs = 32 blocks) + slab cursor init
    prep_k<<<33, 256, 0, stream>>>(w1, w2, wbf1, wbf2, gcur1, gcur2);

    // 2. partition into bucket slabs (dense writes)
    int NB = (E + CHUNK - 1) / CHUNK;   // 196
    partition_k<<<2 * NB, 256, 0, stream>>>(src1, dst1, src2, dst2,
                                            slab1, slab2, gcur1, gcur2, E, NB);

    // 3. in-LDS counting sort -> exact CSR
    csr_k<<<2 * C_BKT, 256, 0, stream>>>(slab1, slab2, gcur1, gcur2,
                                         list1, list2, goff1, goff2,
                                         gcnt1, gcnt2, N);

    // 4. z = x @ w1^T  -> bf16 (MFMA)
    gemm1_mfma_k<<<(N + 63) / 64, 256, 0, stream>>>(x, wbf1, zb, N);

    // 5. fused gather + activation -> s (bf16), column-quartered XCD-affine
    int G = (N + 3) / 4;                          // node groups of 4
    int gblocks = 8 * ((G + 1) / 2);              // 4 quarters x G, %8-mapped
    gather_fuse_k<<<gblocks, 256, 0, stream>>>(zb, goff1, gcnt1, list1,
                                               goff2, gcnt2, list2, b1, sb, N);

    // 6. out = relu(s @ w2^T + b2)  (MFMA, f32 out)
    gemm2_mfma_k<<<(N + 63) / 64, 256, 0, stream>>>(sb, wbf2, b2, out, N);
}

// Round 11
// 207.665 us; speedup vs baseline: 1.0792x; 1.0792x over previous
//
#include <hip/hip_runtime.h>
#include <hip/hip_bf16.h>

// ---------------------------------------------------------------------------
// BidirectionalGINConv: out = relu(0.5*(gin(ei) + gin(rei)))
// Restructured (linearity of segsum; shared w2):
//   z = x@w1^T                 (bf16 MFMA GEMM, epilogue packs z to bf16)
//   adjacency: partition into 256-node bucket slabs -> in-LDS counting sort CSR
//   agg_i = segsum(z[src_i])   (per-node-wave gather, concatenated masked 32-batches)
//   s = 0.5*(relu(z+b1+agg1)+relu(z+b1+agg2))  (fused in gather, bf16 out)
//   out = relu(s@w2^T + b2)    (bf16 MFMA GEMM, f32 epilogue)
// NOTES:
//   r7:  LDS f32 atomicAdd = CAS retry loop on gfx950 -> never on critical path.
//   r8:  prep_k OOB clobbered wbf2 -> 32 conversion blocks + 1 cursor block.
//   r10: XCD-affine column-quartering REGRESSED (55->144us): blockIdx%8->XCD
//        L2 affinity didn't materialize (FETCH rose 151->188MB from 4x list
//        duplication) and per-wave MLP fell 4x. Reverted; never trade MLP for
//        speculative cache locality.
//   r11: gather = one virtual list (c1+c2), 32-wide clamped batches, uniform
//        masks -> all loads independent, no dependent tail rounds.
// ---------------------------------------------------------------------------

#define C_BKT    196     // coarse buckets: b = dst>>8 (256 nodes each)
#define SLAB_CAP 4608    // per-bucket slab capacity; mean 4096 -> +8 sigma
#define CHUNK    4096    // edges per partition block

typedef __attribute__((ext_vector_type(8))) short short8;
typedef __attribute__((ext_vector_type(4))) float f32x4;

__device__ inline unsigned packbf2(float f0, float f1) {   // RNE bf16 pair
    unsigned u0 = __float_as_uint(f0), u1 = __float_as_uint(f1);
    u0 = (u0 + 0x7fffu + ((u0 >> 16) & 1u)) >> 16;
    u1 = (u1 + 0x7fffu + ((u1 >> 16) & 1u)) >> 16;
    return u0 | (u1 << 16);
}

#define BFLO(p) __uint_as_float((p) << 16)
#define BFHI(p) __uint_as_float((p) & 0xffff0000u)

// prep: convert w1,w2 (8192 float2 pairs each) to bf16-packed uints + cursors.
__global__ void prep_k(const float* __restrict__ w1, const float* __restrict__ w2,
                       unsigned* __restrict__ wbf1, unsigned* __restrict__ wbf2,
                       int* __restrict__ gcur1, int* __restrict__ gcur2) {
    int b = blockIdx.x, t = threadIdx.x;
    if (b == 32) {
        if (t < C_BKT) { gcur1[t] = t * SLAB_CAP; gcur2[t] = t * SLAB_CAP; }
        return;
    }
    int p = b * 256 + t;                 // pair index 0..8191
    const float2 v1 = ((const float2*)w1)[p];
    const float2 v2 = ((const float2*)w2)[p];
    wbf1[p] = packbf2(v1.x, v1.y);
    wbf2[p] = packbf2(v2.x, v2.y);
}

// Phase A: partition both edge lists into coarse slabs with DENSE writes.
// Packed record: (dst & 255) << 16 | src   (src < 65536).
__global__ __launch_bounds__(256) void partition_k(
        const int* __restrict__ src1, const int* __restrict__ dst1,
        const int* __restrict__ src2, const int* __restrict__ dst2,
        unsigned* __restrict__ slab1, unsigned* __restrict__ slab2,
        int* __restrict__ gcur1, int* __restrict__ gcur2, int E, int NB) {
    __shared__ unsigned sorted[CHUNK];
    __shared__ unsigned gpos[CHUNK];
    __shared__ int hist[256], loff[256], goff[256], cur[256];

    int t = threadIdx.x;
    int dir = (blockIdx.x >= NB) ? 1 : 0;
    int cb = dir ? (blockIdx.x - NB) : blockIdx.x;
    const int* srcp = dir ? src2 : src1;
    const int* dstp = dir ? dst2 : dst1;
    unsigned* slab = dir ? slab2 : slab1;
    int* gcur = dir ? gcur2 : gcur1;

    hist[t] = 0;
    __syncthreads();

    unsigned vv[16]; int bb[16];
    int base = cb * CHUNK;
    #pragma unroll
    for (int k = 0; k < 16; ++k) {
        int i = base + k * 256 + t;
        if (i < E) {
            int s = srcp[i], d = dstp[i];
            bb[k] = d >> 8;
            vv[k] = ((unsigned)(d & 255) << 16) | (unsigned)s;
            atomicAdd(&hist[bb[k]], 1);
        } else bb[k] = -1;
    }
    __syncthreads();

    int c = hist[t];
    if (t < C_BKT && c > 0) goff[t] = atomicAdd(&gcur[t], c);
    for (int d = 1; d < 256; d <<= 1) {
        int v = (t >= d) ? hist[t - d] : 0;
        __syncthreads();
        hist[t] += v;
        __syncthreads();
    }
    loff[t] = hist[t] - c;
    cur[t] = 0;
    __syncthreads();
    int nv = hist[255];

    #pragma unroll
    for (int k = 0; k < 16; ++k) {
        if (bb[k] >= 0) {
            int b = bb[k];
            int r = atomicAdd(&cur[b], 1);
            int p = loff[b] + r;
            sorted[p] = vv[k];
            int gp = goff[b] + r;
            gpos[p] = (gp < (b + 1) * SLAB_CAP) ? (unsigned)gp : 0xFFFFFFFFu;
        }
    }
    __syncthreads();

    for (int j = t; j < nv; j += 256) {
        unsigned gp = gpos[j];
        if (gp != 0xFFFFFFFFu) slab[gp] = sorted[j];
    }
}

// Phase B: per (bucket, dir): counting-sort slab by node in LDS, emit exact CSR.
__global__ __launch_bounds__(256) void csr_k(
        const unsigned* __restrict__ slab1, const unsigned* __restrict__ slab2,
        const int* __restrict__ gcur1, const int* __restrict__ gcur2,
        unsigned short* __restrict__ list1, unsigned short* __restrict__ list2,
        unsigned* __restrict__ goff1, unsigned* __restrict__ goff2,
        unsigned short* __restrict__ gcnt1, unsigned short* __restrict__ gcnt2,
        int N) {
    __shared__ unsigned short srt[SLAB_CAP];
    __shared__ int cnt[256], loff[256], cur[256];

    int t = threadIdx.x;
    int dir = (blockIdx.x >= C_BKT) ? 1 : 0;
    int b = dir ? (blockIdx.x - C_BKT) : blockIdx.x;
    const unsigned* sl = (dir ? slab2 : slab1) + (size_t)b * SLAB_CAP;
    unsigned short* lst = dir ? list2 : list1;
    unsigned* goffN = dir ? goff2 : goff1;
    unsigned short* gcntN = dir ? gcnt2 : gcnt1;
    int nv = (dir ? gcur2 : gcur1)[b] - b * SLAB_CAP;
    if (nv > SLAB_CAP) nv = SLAB_CAP;

    cnt[t] = 0;
    __syncthreads();
    for (int j = t; j < nv; j += 256) atomicAdd(&cnt[sl[j] >> 16], 1);
    __syncthreads();

    int c = cnt[t];
    for (int d = 1; d < 256; d <<= 1) {
        int v = (t >= d) ? cnt[t - d] : 0;
        __syncthreads();
        cnt[t] += v;
        __syncthreads();
    }
    loff[t] = cnt[t] - c;
    cur[t] = 0;
    int node = b * 256 + t;
    if (node < N) {
        goffN[node] = (unsigned)(b * SLAB_CAP + loff[t]);
        gcntN[node] = (unsigned short)c;
    }
    __syncthreads();

    for (int j = t; j < nv; j += 256) {
        unsigned v = sl[j];
        int n = v >> 16;
        int r = atomicAdd(&cur[n], 1);
        srt[loff[n] + r] = (unsigned short)(v & 0xffffu);
    }
    __syncthreads();
    for (int j = t; j < nv; j += 256)
        lst[(size_t)b * SLAB_CAP + j] = srt[j];
}

// ---------------- MFMA GEMMs (16x16x32 bf16) ----------------
// Block = 256 threads = 4 waves; wave w -> rows [blk*64 + w*16, +16).
// A/B share the same per-lane k-mapping (k-permutation invariant).
// C/D: col=lane&15, row=(lane>>4)*4+reg  [m89-verified].

// GEMM1: A = x (f32, convert on load), out = z packed bf16 (LDS-staged).
__global__ __launch_bounds__(256) void gemm1_mfma_k(
        const float* __restrict__ A, const unsigned* __restrict__ wbf,
        unsigned* __restrict__ zb, int M) {
    __shared__ float cst[64 * 129];
    int t = threadIdx.x;
    int lane = t & 63, wv = t >> 6;
    int l16 = lane & 15, kg = lane >> 4;
    int rowBase = blockIdx.x * 64 + wv * 16;
    int ar = rowBase + l16; if (ar >= M) ar = M - 1;

    f32x4 acc[8];
    #pragma unroll
    for (int ct = 0; ct < 8; ++ct) acc[ct] = (f32x4){0.f, 0.f, 0.f, 0.f};

    const float4* arow = (const float4*)(A + (size_t)ar * 128);
    #pragma unroll
    for (int kt = 0; kt < 4; ++kt) {
        float4 v0 = arow[kt * 8 + kg * 2];
        float4 v1 = arow[kt * 8 + kg * 2 + 1];
        uint4 au = make_uint4(packbf2(v0.x, v0.y), packbf2(v0.z, v0.w),
                              packbf2(v1.x, v1.y), packbf2(v1.z, v1.w));
        short8 a = *(short8*)&au;
        #pragma unroll
        for (int ct = 0; ct < 8; ++ct) {
            uint4 bu = *(const uint4*)(wbf + (size_t)(ct * 16 + l16) * 64 + kt * 16 + kg * 4);
            short8 b = *(short8*)&bu;
            acc[ct] = __builtin_amdgcn_mfma_f32_16x16x32_bf16(a, b, acc[ct], 0, 0, 0);
        }
    }

    #pragma unroll
    for (int ct = 0; ct < 8; ++ct)
        #pragma unroll
        for (int r = 0; r < 4; ++r)
            cst[(wv * 16 + kg * 4 + r) * 129 + ct * 16 + l16] = acc[ct][r];
    __syncthreads();

    int row = t & 63, q = t >> 6;
    int grow = blockIdx.x * 64 + row;
    if (grow < M) {
        const float* src = cst + row * 129 + q * 32;
        unsigned pk[16];
        #pragma unroll
        for (int i = 0; i < 16; ++i) pk[i] = packbf2(src[2 * i], src[2 * i + 1]);
        uint4* dst = (uint4*)(zb + (size_t)grow * 64 + q * 16);
        #pragma unroll
        for (int qq = 0; qq < 4; ++qq)
            dst[qq] = make_uint4(pk[4 * qq], pk[4 * qq + 1], pk[4 * qq + 2], pk[4 * qq + 3]);
    }
}

// GEMM2: A = s (bf16), out = relu(A@W^T + b2) f32. Direct stores.
__global__ __launch_bounds__(256) void gemm2_mfma_k(
        const unsigned* __restrict__ sB, const unsigned* __restrict__ wbf,
        const float* __restrict__ bias, float* __restrict__ O, int M) {
    int t = threadIdx.x;
    int lane = t & 63, wv = t >> 6;
    int l16 = lane & 15, kg = lane >> 4;
    int rowBase = blockIdx.x * 64 + wv * 16;
    int ar = rowBase + l16; if (ar >= M) ar = M - 1;

    f32x4 acc[8];
    #pragma unroll
    for (int ct = 0; ct < 8; ++ct) acc[ct] = (f32x4){0.f, 0.f, 0.f, 0.f};

    #pragma unroll
    for (int kt = 0; kt < 4; ++kt) {
        uint4 au = *(const uint4*)(sB + (size_t)ar * 64 + kt * 16 + kg * 4);
        short8 a = *(short8*)&au;
        #pragma unroll
        for (int ct = 0; ct < 8; ++ct) {
            uint4 bu = *(const uint4*)(wbf + (size_t)(ct * 16 + l16) * 64 + kt * 16 + kg * 4);
            short8 b = *(short8*)&bu;
            acc[ct] = __builtin_amdgcn_mfma_f32_16x16x32_bf16(a, b, acc[ct], 0, 0, 0);
        }
    }

    #pragma unroll
    for (int ct = 0; ct < 8; ++ct) {
        int col = ct * 16 + l16;
        float bv = bias[col];
        #pragma unroll
        for (int r = 0; r < 4; ++r) {
            int grow = rowBase + kg * 4 + r;
            if (grow < M)
                O[(size_t)grow * 128 + col] = fmaxf(acc[ct][r] + bv, 0.f);
        }
    }
}

// ---------------- gather: concatenated masked 32-batches ----------------
// One node per 64-lane wave (g wave-uniform -> list/count loads are scalar).
// Both directions form one virtual list of length c1+c2 (mean 32); each loop
// iteration issues 32 INDEPENDENT z-row loads (clamped indices for the tail,
// uniform masks route values to agg1/agg2; clamp-waste loads are L1 hits).
__global__ __launch_bounds__(256) void gather_fuse_k(
        const unsigned* __restrict__ zb,
        const unsigned* __restrict__ goff1, const unsigned short* __restrict__ gcnt1,
        const unsigned short* __restrict__ list1,
        const unsigned* __restrict__ goff2, const unsigned short* __restrict__ gcnt2,
        const unsigned short* __restrict__ list2,
        const float* __restrict__ b1, unsigned* __restrict__ sOut, int N) {
    int g = __builtin_amdgcn_readfirstlane(blockIdx.x * 4 + (threadIdx.x >> 6));
    if (g >= N) return;
    int lane = threadIdx.x & 63;

    int o1 = (int)goff1[g], c1 = (int)gcnt1[g];
    int o2 = (int)goff2[g], c2 = (int)gcnt2[g];
    int ctot = c1 + c2;

    float a1x = 0.f, a1y = 0.f, a2x = 0.f, a2y = 0.f;

    for (int base = 0; base < ctot; base += 32) {
        unsigned pv[32];
        #pragma unroll
        for (int u = 0; u < 32; ++u) {
            int e = base + u; if (e > ctot - 1) e = ctot - 1;   // clamp (uniform)
            const unsigned short* lp = (e < c1) ? (list1 + o1 + e)
                                                : (list2 + o2 + (e - c1));
            pv[u] = zb[(size_t)(*lp) * 64 + lane];
        }
        float s1x = 0.f, s1y = 0.f, s2x = 0.f, s2y = 0.f;
        #pragma unroll
        for (int u = 0; u < 32; ++u) {
            int e = base + u;
            if (e < ctot) {                    // uniform masks
                if (e < c1) { s1x += BFLO(pv[u]); s1y += BFHI(pv[u]); }
                else        { s2x += BFLO(pv[u]); s2y += BFHI(pv[u]); }
            }
        }
        a1x += s1x; a1y += s1y; a2x += s2x; a2y += s2y;
    }

    unsigned pz = zb[(size_t)g * 64 + lane];
    float2 bb = ((const float2*)b1)[lane];
    float bx = BFLO(pz) + bb.x, by = BFHI(pz) + bb.y;
    float ox = 0.5f * (fmaxf(bx + a1x, 0.f) + fmaxf(bx + a2x, 0.f));
    float oy = 0.5f * (fmaxf(by + a1y, 0.f) + fmaxf(by + a2y, 0.f));
    sOut[(size_t)g * 64 + lane] = packbf2(ox, oy);
}

extern "C" void kernel_launch(void* const* d_in, const int* in_sizes, int n_in,
                              void* d_out, int out_size, void* d_ws, size_t ws_size,
                              hipStream_t stream) {
    const float* x   = (const float*)d_in[0];
    const int*   ei  = (const int*)d_in[1];
    const int*   rei = (const int*)d_in[2];
    const float* w1  = (const float*)d_in[3];
    const float* b1  = (const float*)d_in[4];
    const float* w2  = (const float*)d_in[5];
    const float* b2  = (const float*)d_in[6];
    float* out = (float*)d_out;

    const int N = in_sizes[0] / 128;      // 50000
    const int E = in_sizes[1] / 2;        // 800000
    const size_t ND = (size_t)N * 128;
    const size_t SL = (size_t)C_BKT * SLAB_CAP;   // 903168

    // ws layout (~38 MB)
    unsigned* zb    = (unsigned*)d_ws;            // N*64  (bf16 z, 12.8 MB)
    unsigned* sb    = zb + ND / 2;                // N*64  (bf16 s, 12.8 MB)
    unsigned* wbf1  = sb + ND / 2;                // 8192  (bf16 w1, 32 KB)
    unsigned* wbf2  = wbf1 + 8192;                // 8192
    unsigned* slab1 = wbf2 + 8192;                // SL
    unsigned* slab2 = slab1 + SL;                 // SL
    unsigned* goff1 = slab2 + SL;                 // N
    unsigned* goff2 = goff1 + N;                  // N
    int*      gcur1 = (int*)(goff2 + N);          // C_BKT
    int*      gcur2 = gcur1 + C_BKT;              // C_BKT
    unsigned short* gcnt1 = (unsigned short*)(gcur2 + C_BKT);  // N
    unsigned short* gcnt2 = gcnt1 + N;            // N
    unsigned short* list1 = gcnt2 + N;            // SL
    unsigned short* list2 = list1 + SL;           // SL

    const int* src1 = ei,  *dst1 = ei + E;
    const int* src2 = rei, *dst2 = rei + E;

    // 1. weight bf16 convert (8192 pairs = 32 blocks) + slab cursor init
    prep_k<<<33, 256, 0, stream>>>(w1, w2, wbf1, wbf2, gcur1, gcur2);

    // 2. partition into bucket slabs (dense writes)
    int NB = (E + CHUNK - 1) / CHUNK;   // 196
    partition_k<<<2 * NB, 256, 0, stream>>>(src1, dst1, src2, dst2,
                                            slab1, slab2, gcur1, gcur2, E, NB);

    // 3. in-LDS counting sort -> exact CSR
    csr_k<<<2 * C_BKT, 256, 0, stream>>>(slab1, slab2, gcur1, gcur2,
                                         list1, list2, goff1, goff2,
                                         gcnt1, gcnt2, N);

    // 4. z = x @ w1^T  -> bf16 (MFMA)
    gemm1_mfma_k<<<(N + 63) / 64, 256, 0, stream>>>(x, wbf1, zb, N);

    // 5. fused gather + activation -> s (bf16)
    gather_fuse_k<<<(N + 3) / 4, 256, 0, stream>>>(zb, goff1, gcnt1, list1,
                                                   goff2, gcnt2, list2, b1, sb, N);

    // 6. out = relu(s @ w2^T + b2)  (MFMA, f32 out)
    gemm2_mfma_k<<<(N + 63) / 64, 256, 0, stream>>>(sb, wbf2, b2, out, N);
}

// Round 12
// 163.280 us; speedup vs baseline: 1.3726x; 1.2718x over previous
//
#include <hip/hip_runtime.h>
#include <hip/hip_bf16.h>

// ---------------------------------------------------------------------------
// BidirectionalGINConv: out = relu(0.5*(gin(ei) + gin(rei)))
// Restructured (linearity of segsum; shared w2):
//   z = x@w1^T                 (bf16 MFMA GEMM, fused into partition launch)
//   adjacency: partition into 256-node bucket slabs -> in-LDS counting sort CSR
//   agg_i = segsum(z[src_i])   (4-waves-per-node gather, LDS cross-wave reduce)
//   s = 0.5*(relu(z+b1+agg1)+relu(z+b1+agg2))  (fused in gather, bf16 out)
//   out = relu(s@w2^T + b2)    (bf16 MFMA GEMM, f32 epilogue)
// NOTES:
//   r7:  LDS f32 atomicAdd = CAS retry loop on gfx950 -> never on critical path.
//   r8:  prep_k OOB clobbered wbf2 -> 32 conversion blocks + 1 cursor block.
//   r10: XCD-affine column-quartering regressed (55->144us): no L2 affinity,
//        4x list duplication, 4x less MLP/wave. Never trade MLP for
//        speculative cache locality.
//   r11: 32-wide virtual-list batch regressed (55->129us): VGPR_Count=40 shows
//        the compiler never kept the 32-deep batch in registers; it serialized
//        into chunks + per-element pointer selects. Batches >16 are unreliable.
//   r12: split the node across 4 waves (8-deep batches each, LDS reduce) ->
//        ~4 dependent phases/wave vs ~9; fuse partition || gemm1 (block-range
//        dispatch) since graph capture forbids multi-stream overlap.
// ---------------------------------------------------------------------------

#define C_BKT    196     // coarse buckets: b = dst>>8 (256 nodes each)
#define SLAB_CAP 4608    // per-bucket slab capacity; mean 4096 -> +8 sigma
#define CHUNK    4096    // edges per partition block

typedef __attribute__((ext_vector_type(8))) short short8;
typedef __attribute__((ext_vector_type(4))) float f32x4;

__device__ inline unsigned packbf2(float f0, float f1) {   // RNE bf16 pair
    unsigned u0 = __float_as_uint(f0), u1 = __float_as_uint(f1);
    u0 = (u0 + 0x7fffu + ((u0 >> 16) & 1u)) >> 16;
    u1 = (u1 + 0x7fffu + ((u1 >> 16) & 1u)) >> 16;
    return u0 | (u1 << 16);
}

#define BFLO(p) __uint_as_float((p) << 16)
#define BFHI(p) __uint_as_float((p) & 0xffff0000u)

// prep: convert w1,w2 (8192 float2 pairs each) to bf16-packed uints + cursors.
__global__ void prep_k(const float* __restrict__ w1, const float* __restrict__ w2,
                       unsigned* __restrict__ wbf1, unsigned* __restrict__ wbf2,
                       int* __restrict__ gcur1, int* __restrict__ gcur2) {
    int b = blockIdx.x, t = threadIdx.x;
    if (b == 32) {
        if (t < C_BKT) { gcur1[t] = t * SLAB_CAP; gcur2[t] = t * SLAB_CAP; }
        return;
    }
    int p = b * 256 + t;                 // pair index 0..8191
    const float2 v1 = ((const float2*)w1)[p];
    const float2 v2 = ((const float2*)w2)[p];
    wbf1[p] = packbf2(v1.x, v1.y);
    wbf2[p] = packbf2(v2.x, v2.y);
}

// ---------------- fused partition || gemm1 ----------------
// blocks [0, 2*NB)            : partition both edge lists into bucket slabs
// blocks [2*NB, 2*NB+gblocks) : z = x @ w1^T -> bf16 (MFMA)
// 36 KB shared union; bodies are independent kernels sharing one dispatch.

__device__ void partition_body(char* smem, int bx,
        const int* __restrict__ src1, const int* __restrict__ dst1,
        const int* __restrict__ src2, const int* __restrict__ dst2,
        unsigned* __restrict__ slab1, unsigned* __restrict__ slab2,
        int* __restrict__ gcur1, int* __restrict__ gcur2, int E, int NB) {
    unsigned* sorted = (unsigned*)smem;              // 16 KB
    unsigned* gpos   = sorted + CHUNK;               // 16 KB
    int* hist = (int*)(gpos + CHUNK);                // 1 KB
    int* loff = hist + 256;
    int* goff = loff + 256;
    int* cur  = goff + 256;

    int t = threadIdx.x;
    int dir = (bx >= NB) ? 1 : 0;
    int cb = dir ? (bx - NB) : bx;
    const int* srcp = dir ? src2 : src1;
    const int* dstp = dir ? dst2 : dst1;
    unsigned* slab = dir ? slab2 : slab1;
    int* gcur = dir ? gcur2 : gcur1;

    hist[t] = 0;
    __syncthreads();

    unsigned vv[16]; int bb[16];
    int base = cb * CHUNK;
    #pragma unroll
    for (int k = 0; k < 16; ++k) {
        int i = base + k * 256 + t;
        if (i < E) {
            int s = srcp[i], d = dstp[i];
            bb[k] = d >> 8;
            vv[k] = ((unsigned)(d & 255) << 16) | (unsigned)s;
            atomicAdd(&hist[bb[k]], 1);
        } else bb[k] = -1;
    }
    __syncthreads();

    int c = hist[t];
    if (t < C_BKT && c > 0) goff[t] = atomicAdd(&gcur[t], c);
    for (int d = 1; d < 256; d <<= 1) {
        int v = (t >= d) ? hist[t - d] : 0;
        __syncthreads();
        hist[t] += v;
        __syncthreads();
    }
    loff[t] = hist[t] - c;
    cur[t] = 0;
    __syncthreads();
    int nv = hist[255];

    #pragma unroll
    for (int k = 0; k < 16; ++k) {
        if (bb[k] >= 0) {
            int b = bb[k];
            int r = atomicAdd(&cur[b], 1);
            int p = loff[b] + r;
            sorted[p] = vv[k];
            int gp = goff[b] + r;
            gpos[p] = (gp < (b + 1) * SLAB_CAP) ? (unsigned)gp : 0xFFFFFFFFu;
        }
    }
    __syncthreads();

    for (int j = t; j < nv; j += 256) {
        unsigned gp = gpos[j];
        if (gp != 0xFFFFFFFFu) slab[gp] = sorted[j];
    }
}

// MFMA 16x16x32 bf16. Block = 4 waves; wave w -> rows [bx*64 + w*16, +16).
// A/B share the same per-lane k-mapping (k-permutation invariant).
// C/D: col=lane&15, row=(lane>>4)*4+reg  [m89-verified].
__device__ void gemm1_body(char* smem, int bx,
        const float* __restrict__ A, const unsigned* __restrict__ wbf,
        unsigned* __restrict__ zb, int M) {
    float* cst = (float*)smem;                       // 64*129*4 = 33 KB
    int t = threadIdx.x;
    int lane = t & 63, wv = t >> 6;
    int l16 = lane & 15, kg = lane >> 4;
    int rowBase = bx * 64 + wv * 16;
    int ar = rowBase + l16; if (ar >= M) ar = M - 1;

    f32x4 acc[8];
    #pragma unroll
    for (int ct = 0; ct < 8; ++ct) acc[ct] = (f32x4){0.f, 0.f, 0.f, 0.f};

    const float4* arow = (const float4*)(A + (size_t)ar * 128);
    #pragma unroll
    for (int kt = 0; kt < 4; ++kt) {
        float4 v0 = arow[kt * 8 + kg * 2];
        float4 v1 = arow[kt * 8 + kg * 2 + 1];
        uint4 au = make_uint4(packbf2(v0.x, v0.y), packbf2(v0.z, v0.w),
                              packbf2(v1.x, v1.y), packbf2(v1.z, v1.w));
        short8 a = *(short8*)&au;
        #pragma unroll
        for (int ct = 0; ct < 8; ++ct) {
            uint4 bu = *(const uint4*)(wbf + (size_t)(ct * 16 + l16) * 64 + kt * 16 + kg * 4);
            short8 b = *(short8*)&bu;
            acc[ct] = __builtin_amdgcn_mfma_f32_16x16x32_bf16(a, b, acc[ct], 0, 0, 0);
        }
    }

    #pragma unroll
    for (int ct = 0; ct < 8; ++ct)
        #pragma unroll
        for (int r = 0; r < 4; ++r)
            cst[(wv * 16 + kg * 4 + r) * 129 + ct * 16 + l16] = acc[ct][r];
    __syncthreads();

    int row = t & 63, q = t >> 6;
    int grow = bx * 64 + row;
    if (grow < M) {
        const float* src = cst + row * 129 + q * 32;
        unsigned pk[16];
        #pragma unroll
        for (int i = 0; i < 16; ++i) pk[i] = packbf2(src[2 * i], src[2 * i + 1]);
        uint4* dst = (uint4*)(zb + (size_t)grow * 64 + q * 16);
        #pragma unroll
        for (int qq = 0; qq < 4; ++qq)
            dst[qq] = make_uint4(pk[4 * qq], pk[4 * qq + 1], pk[4 * qq + 2], pk[4 * qq + 3]);
    }
}

__global__ __launch_bounds__(256) void pg_k(
        const int* __restrict__ src1, const int* __restrict__ dst1,
        const int* __restrict__ src2, const int* __restrict__ dst2,
        unsigned* __restrict__ slab1, unsigned* __restrict__ slab2,
        int* __restrict__ gcur1, int* __restrict__ gcur2, int E, int NB,
        const float* __restrict__ x, const unsigned* __restrict__ wbf1,
        unsigned* __restrict__ zb, int M) {
    __shared__ __align__(16) char smem[36864];
    int bx = blockIdx.x;
    if (bx < 2 * NB)
        partition_body(smem, bx, src1, dst1, src2, dst2,
                       slab1, slab2, gcur1, gcur2, E, NB);
    else
        gemm1_body(smem, bx - 2 * NB, x, wbf1, zb, M);
}

// Phase B: per (bucket, dir): counting-sort slab by node in LDS, emit exact CSR.
__global__ __launch_bounds__(256) void csr_k(
        const unsigned* __restrict__ slab1, const unsigned* __restrict__ slab2,
        const int* __restrict__ gcur1, const int* __restrict__ gcur2,
        unsigned short* __restrict__ list1, unsigned short* __restrict__ list2,
        unsigned* __restrict__ goff1, unsigned* __restrict__ goff2,
        unsigned short* __restrict__ gcnt1, unsigned short* __restrict__ gcnt2,
        int N) {
    __shared__ unsigned short srt[SLAB_CAP];
    __shared__ int cnt[256], loff[256], cur[256];

    int t = threadIdx.x;
    int dir = (blockIdx.x >= C_BKT) ? 1 : 0;
    int b = dir ? (blockIdx.x - C_BKT) : blockIdx.x;
    const unsigned* sl = (dir ? slab2 : slab1) + (size_t)b * SLAB_CAP;
    unsigned short* lst = dir ? list2 : list1;
    unsigned* goffN = dir ? goff2 : goff1;
    unsigned short* gcntN = dir ? gcnt2 : gcnt1;
    int nv = (dir ? gcur2 : gcur1)[b] - b * SLAB_CAP;
    if (nv > SLAB_CAP) nv = SLAB_CAP;

    cnt[t] = 0;
    __syncthreads();
    for (int j = t; j < nv; j += 256) atomicAdd(&cnt[sl[j] >> 16], 1);
    __syncthreads();

    int c = cnt[t];
    for (int d = 1; d < 256; d <<= 1) {
        int v = (t >= d) ? cnt[t - d] : 0;
        __syncthreads();
        cnt[t] += v;
        __syncthreads();
    }
    loff[t] = cnt[t] - c;
    cur[t] = 0;
    int node = b * 256 + t;
    if (node < N) {
        goffN[node] = (unsigned)(b * SLAB_CAP + loff[t]);
        gcntN[node] = (unsigned short)c;
    }
    __syncthreads();

    for (int j = t; j < nv; j += 256) {
        unsigned v = sl[j];
        int n = v >> 16;
        int r = atomicAdd(&cur[n], 1);
        srt[loff[n] + r] = (unsigned short)(v & 0xffffu);
    }
    __syncthreads();
    for (int j = t; j < nv; j += 256)
        lst[(size_t)b * SLAB_CAP + j] = srt[j];
}

// GEMM2: A = s (bf16), out = relu(A@W^T + b2) f32. Direct stores.
__global__ __launch_bounds__(256) void gemm2_mfma_k(
        const unsigned* __restrict__ sB, const unsigned* __restrict__ wbf,
        const float* __restrict__ bias, float* __restrict__ O, int M) {
    int t = threadIdx.x;
    int lane = t & 63, wv = t >> 6;
    int l16 = lane & 15, kg = lane >> 4;
    int rowBase = blockIdx.x * 64 + wv * 16;
    int ar = rowBase + l16; if (ar >= M) ar = M - 1;

    f32x4 acc[8];
    #pragma unroll
    for (int ct = 0; ct < 8; ++ct) acc[ct] = (f32x4){0.f, 0.f, 0.f, 0.f};

    #pragma unroll
    for (int kt = 0; kt < 4; ++kt) {
        uint4 au = *(const uint4*)(sB + (size_t)ar * 64 + kt * 16 + kg * 4);
        short8 a = *(short8*)&au;
        #pragma unroll
        for (int ct = 0; ct < 8; ++ct) {
            uint4 bu = *(const uint4*)(wbf + (size_t)(ct * 16 + l16) * 64 + kt * 16 + kg * 4);
            short8 b = *(short8*)&bu;
            acc[ct] = __builtin_amdgcn_mfma_f32_16x16x32_bf16(a, b, acc[ct], 0, 0, 0);
        }
    }

    #pragma unroll
    for (int ct = 0; ct < 8; ++ct) {
        int col = ct * 16 + l16;
        float bv = bias[col];
        #pragma unroll
        for (int r = 0; r < 4; ++r) {
            int grow = rowBase + kg * 4 + r;
            if (grow < M)
                O[(size_t)grow * 128 + col] = fmaxf(acc[ct][r] + bv, 0.f);
        }
    }
}

// ---------------- gather: 4 waves per node, LDS cross-wave reduce ----------
// Block = 1 node. The concatenated list (c1+c2, mean 32) splits into 4 wave
// slices (~8 edges). Per wave: ONE idx phase + ONE z phase (8-deep batches,
// register-friendly), plain per-direction base pointers (no per-element
// pointer selects). Partials -> LDS, wave 0 reduces + fused activation.
__global__ __launch_bounds__(256) void gather_fuse_k(
        const unsigned* __restrict__ zb,
        const unsigned* __restrict__ goff1, const unsigned short* __restrict__ gcnt1,
        const unsigned short* __restrict__ list1,
        const unsigned* __restrict__ goff2, const unsigned short* __restrict__ gcnt2,
        const unsigned short* __restrict__ list2,
        const float* __restrict__ b1, unsigned* __restrict__ sOut, int N) {
    __shared__ float red[4][4][64];
    int g = blockIdx.x;
    int t = threadIdx.x;
    int w = t >> 6, lane = t & 63;

    int o1 = (int)goff1[g], c1 = (int)gcnt1[g];
    int o2 = (int)goff2[g], c2 = (int)gcnt2[g];
    int ctot = c1 + c2;

    float s1x = 0.f, s1y = 0.f, s2x = 0.f, s2y = 0.f;

    int work = (ctot + 3) >> 2;
    int lo = w * work;
    int hi = lo + work;
    if (hi > ctot) hi = ctot;
    if (lo > ctot) lo = ctot;

    // dir1 part of this wave's slice: [lo, min(hi, c1))
    {
        int dhi = (hi < c1) ? hi : c1;
        for (int b = lo; b < dhi; b += 8) {
            int n = dhi - b; if (n > 8) n = 8;
            unsigned idx[8], pv[8];
            #pragma unroll
            for (int u = 0; u < 8; ++u) {
                int e = (u < n) ? (b + u) : (b + n - 1);   // clamp (uniform)
                idx[u] = list1[o1 + e];
            }
            #pragma unroll
            for (int u = 0; u < 8; ++u) pv[u] = zb[(size_t)idx[u] * 64 + lane];
            #pragma unroll
            for (int u = 0; u < 8; ++u)
                if (u < n) { s1x += BFLO(pv[u]); s1y += BFHI(pv[u]); }
        }
    }
    // dir2 part of this wave's slice: [max(lo, c1), hi) -> list2[e - c1]
    {
        int dlo = (lo > c1) ? lo : c1;
        for (int b = dlo; b < hi; b += 8) {
            int n = hi - b; if (n > 8) n = 8;
            unsigned idx[8], pv[8];
            #pragma unroll
            for (int u = 0; u < 8; ++u) {
                int e = (u < n) ? (b + u) : (b + n - 1);
                idx[u] = list2[o2 + (e - c1)];
            }
            #pragma unroll
            for (int u = 0; u < 8; ++u) pv[u] = zb[(size_t)idx[u] * 64 + lane];
            #pragma unroll
            for (int u = 0; u < 8; ++u)
                if (u < n) { s2x += BFLO(pv[u]); s2y += BFHI(pv[u]); }
        }
    }

    red[w][0][lane] = s1x;
    red[w][1][lane] = s1y;
    red[w][2][lane] = s2x;
    red[w][3][lane] = s2y;
    __syncthreads();
    if (w != 0) return;

    float a1x = red[0][0][lane] + red[1][0][lane] + red[2][0][lane] + red[3][0][lane];
    float a1y = red[0][1][lane] + red[1][1][lane] + red[2][1][lane] + red[3][1][lane];
    float a2x = red[0][2][lane] + red[1][2][lane] + red[2][2][lane] + red[3][2][lane];
    float a2y = red[0][3][lane] + red[1][3][lane] + red[2][3][lane] + red[3][3][lane];

    unsigned pz = zb[(size_t)g * 64 + lane];
    float2 bb = ((const float2*)b1)[lane];
    float bx = BFLO(pz) + bb.x, by = BFHI(pz) + bb.y;
    float ox = 0.5f * (fmaxf(bx + a1x, 0.f) + fmaxf(bx + a2x, 0.f));
    float oy = 0.5f * (fmaxf(by + a1y, 0.f) + fmaxf(by + a2y, 0.f));
    sOut[(size_t)g * 64 + lane] = packbf2(ox, oy);
}

extern "C" void kernel_launch(void* const* d_in, const int* in_sizes, int n_in,
                              void* d_out, int out_size, void* d_ws, size_t ws_size,
                              hipStream_t stream) {
    const float* x   = (const float*)d_in[0];
    const int*   ei  = (const int*)d_in[1];
    const int*   rei = (const int*)d_in[2];
    const float* w1  = (const float*)d_in[3];
    const float* b1  = (const float*)d_in[4];
    const float* w2  = (const float*)d_in[5];
    const float* b2  = (const float*)d_in[6];
    float* out = (float*)d_out;

    const int N = in_sizes[0] / 128;      // 50000
    const int E = in_sizes[1] / 2;        // 800000
    const size_t ND = (size_t)N * 128;
    const size_t SL = (size_t)C_BKT * SLAB_CAP;   // 903168

    // ws layout (~38 MB)
    unsigned* zb    = (unsigned*)d_ws;            // N*64  (bf16 z, 12.8 MB)
    unsigned* sb    = zb + ND / 2;                // N*64  (bf16 s, 12.8 MB)
    unsigned* wbf1  = sb + ND / 2;                // 8192  (bf16 w1, 32 KB)
    unsigned* wbf2  = wbf1 + 8192;                // 8192
    unsigned* slab1 = wbf2 + 8192;                // SL
    unsigned* slab2 = slab1 + SL;                 // SL
    unsigned* goff1 = slab2 + SL;                 // N
    unsigned* goff2 = goff1 + N;                  // N
    int*      gcur1 = (int*)(goff2 + N);          // C_BKT
    int*      gcur2 = gcur1 + C_BKT;              // C_BKT
    unsigned short* gcnt1 = (unsigned short*)(gcur2 + C_BKT);  // N
    unsigned short* gcnt2 = gcnt1 + N;            // N
    unsigned short* list1 = gcnt2 + N;            // SL
    unsigned short* list2 = list1 + SL;           // SL

    const int* src1 = ei,  *dst1 = ei + E;
    const int* src2 = rei, *dst2 = rei + E;

    // 1. weight bf16 convert (8192 pairs = 32 blocks) + slab cursor init
    prep_k<<<33, 256, 0, stream>>>(w1, w2, wbf1, wbf2, gcur1, gcur2);

    // 2. fused: partition (392 blocks) || gemm1 (782 blocks)
    int NB = (E + CHUNK - 1) / CHUNK;   // 196
    int gB = (N + 63) / 64;             // 782
    pg_k<<<2 * NB + gB, 256, 0, stream>>>(src1, dst1, src2, dst2,
                                          slab1, slab2, gcur1, gcur2, E, NB,
                                          x, wbf1, zb, N);

    // 3. in-LDS counting sort -> exact CSR
    csr_k<<<2 * C_BKT, 256, 0, stream>>>(slab1, slab2, gcur1, gcur2,
                                         list1, list2, goff1, goff2,
                                         gcnt1, gcnt2, N);

    // 4. fused gather + activation -> s (bf16); 1 node per block, 4 waves
    gather_fuse_k<<<N, 256, 0, stream>>>(zb, goff1, gcnt1, list1,
                                         goff2, gcnt2, list2, b1, sb, N);

    // 5. out = relu(s @ w2^T + b2)  (MFMA, f32 out)
    gemm2_mfma_k<<<gB, 256, 0, stream>>>(sb, wbf2, b2, out, N);
}

// Round 13
// 123.961 us; speedup vs baseline: 1.8079x; 1.3172x over previous
//
#include <hip/hip_runtime.h>
#include <hip/hip_bf16.h>

// ---------------------------------------------------------------------------
// BidirectionalGINConv: out = relu(0.5*(gin(ei) + gin(rei)))
// Restructured (linearity of segsum; shared w2):
//   z = x@w1^T                 (bf16 MFMA GEMM, fused into partition launch)
//   adjacency: partition into 256-node bucket slabs -> in-LDS counting sort CSR
//   agg_i = segsum(z[src_i])   (1-node-per-wave gather, 16/8/4 batches — r9)
//   s = 0.5*(relu(z+b1+agg1)+relu(z+b1+agg2))  (fused in gather, bf16 out)
//   out = relu(s@w2^T + b2)    (bf16 MFMA GEMM, f32 epilogue)
// NOTES:
//   r7:  LDS f32 atomicAdd = CAS retry loop on gfx950 -> never on critical path.
//   r8:  prep_k OOB clobbered wbf2 -> 32 conversion blocks + 1 cursor block.
//   r10: XCD-affine column-quartering regressed (55->144us): no L2 affinity,
//        4x list duplication, 4x less MLP/wave.
//   r11: 32-wide virtual-list batch regressed (55->129us): compiler can't keep
//        32-deep batches in registers; serialized + pointer-select SALU chains.
//   r12: 4-waves-per-node regressed gather (55->98us, VALUBusy 66% = pure
//        overhead), but partition||gemm1 fusion SAVED ~17us on the rest.
//   r13: r9 gather verbatim + r12 fusion. Gather restructures are exhausted;
//        55us @ 2.75TB/s L2-miss traffic is the working LLC-service floor.
// ---------------------------------------------------------------------------

#define C_BKT    196     // coarse buckets: b = dst>>8 (256 nodes each)
#define SLAB_CAP 4608    // per-bucket slab capacity; mean 4096 -> +8 sigma
#define CHUNK    4096    // edges per partition block

typedef __attribute__((ext_vector_type(8))) short short8;
typedef __attribute__((ext_vector_type(4))) float f32x4;

__device__ inline unsigned packbf2(float f0, float f1) {   // RNE bf16 pair
    unsigned u0 = __float_as_uint(f0), u1 = __float_as_uint(f1);
    u0 = (u0 + 0x7fffu + ((u0 >> 16) & 1u)) >> 16;
    u1 = (u1 + 0x7fffu + ((u1 >> 16) & 1u)) >> 16;
    return u0 | (u1 << 16);
}

#define BFLO(p) __uint_as_float((p) << 16)
#define BFHI(p) __uint_as_float((p) & 0xffff0000u)

// prep: convert w1,w2 (8192 float2 pairs each) to bf16-packed uints + cursors.
__global__ void prep_k(const float* __restrict__ w1, const float* __restrict__ w2,
                       unsigned* __restrict__ wbf1, unsigned* __restrict__ wbf2,
                       int* __restrict__ gcur1, int* __restrict__ gcur2) {
    int b = blockIdx.x, t = threadIdx.x;
    if (b == 32) {
        if (t < C_BKT) { gcur1[t] = t * SLAB_CAP; gcur2[t] = t * SLAB_CAP; }
        return;
    }
    int p = b * 256 + t;                 // pair index 0..8191
    const float2 v1 = ((const float2*)w1)[p];
    const float2 v2 = ((const float2*)w2)[p];
    wbf1[p] = packbf2(v1.x, v1.y);
    wbf2[p] = packbf2(v2.x, v2.y);
}

// ---------------- fused partition || gemm1 ----------------
// blocks [0, 2*NB)            : partition both edge lists into bucket slabs
// blocks [2*NB, 2*NB+gblocks) : z = x @ w1^T -> bf16 (MFMA)

__device__ void partition_body(char* smem, int bx,
        const int* __restrict__ src1, const int* __restrict__ dst1,
        const int* __restrict__ src2, const int* __restrict__ dst2,
        unsigned* __restrict__ slab1, unsigned* __restrict__ slab2,
        int* __restrict__ gcur1, int* __restrict__ gcur2, int E, int NB) {
    unsigned* sorted = (unsigned*)smem;              // 16 KB
    unsigned* gpos   = sorted + CHUNK;               // 16 KB
    int* hist = (int*)(gpos + CHUNK);                // 1 KB
    int* loff = hist + 256;
    int* goff = loff + 256;
    int* cur  = goff + 256;

    int t = threadIdx.x;
    int dir = (bx >= NB) ? 1 : 0;
    int cb = dir ? (bx - NB) : bx;
    const int* srcp = dir ? src2 : src1;
    const int* dstp = dir ? dst2 : dst1;
    unsigned* slab = dir ? slab2 : slab1;
    int* gcur = dir ? gcur2 : gcur1;

    hist[t] = 0;
    __syncthreads();

    unsigned vv[16]; int bb[16];
    int base = cb * CHUNK;
    #pragma unroll
    for (int k = 0; k < 16; ++k) {
        int i = base + k * 256 + t;
        if (i < E) {
            int s = srcp[i], d = dstp[i];
            bb[k] = d >> 8;
            vv[k] = ((unsigned)(d & 255) << 16) | (unsigned)s;
            atomicAdd(&hist[bb[k]], 1);
        } else bb[k] = -1;
    }
    __syncthreads();

    int c = hist[t];
    if (t < C_BKT && c > 0) goff[t] = atomicAdd(&gcur[t], c);
    for (int d = 1; d < 256; d <<= 1) {
        int v = (t >= d) ? hist[t - d] : 0;
        __syncthreads();
        hist[t] += v;
        __syncthreads();
    }
    loff[t] = hist[t] - c;
    cur[t] = 0;
    __syncthreads();
    int nv = hist[255];

    #pragma unroll
    for (int k = 0; k < 16; ++k) {
        if (bb[k] >= 0) {
            int b = bb[k];
            int r = atomicAdd(&cur[b], 1);
            int p = loff[b] + r;
            sorted[p] = vv[k];
            int gp = goff[b] + r;
            gpos[p] = (gp < (b + 1) * SLAB_CAP) ? (unsigned)gp : 0xFFFFFFFFu;
        }
    }
    __syncthreads();

    for (int j = t; j < nv; j += 256) {
        unsigned gp = gpos[j];
        if (gp != 0xFFFFFFFFu) slab[gp] = sorted[j];
    }
}

// MFMA 16x16x32 bf16. Block = 4 waves; wave w -> rows [bx*64 + w*16, +16).
// A/B share the same per-lane k-mapping (k-permutation invariant).
// C/D: col=lane&15, row=(lane>>4)*4+reg  [m89-verified].
__device__ void gemm1_body(char* smem, int bx,
        const float* __restrict__ A, const unsigned* __restrict__ wbf,
        unsigned* __restrict__ zb, int M) {
    float* cst = (float*)smem;                       // 64*129*4 = 33 KB
    int t = threadIdx.x;
    int lane = t & 63, wv = t >> 6;
    int l16 = lane & 15, kg = lane >> 4;
    int rowBase = bx * 64 + wv * 16;
    int ar = rowBase + l16; if (ar >= M) ar = M - 1;

    f32x4 acc[8];
    #pragma unroll
    for (int ct = 0; ct < 8; ++ct) acc[ct] = (f32x4){0.f, 0.f, 0.f, 0.f};

    const float4* arow = (const float4*)(A + (size_t)ar * 128);
    #pragma unroll
    for (int kt = 0; kt < 4; ++kt) {
        float4 v0 = arow[kt * 8 + kg * 2];
        float4 v1 = arow[kt * 8 + kg * 2 + 1];
        uint4 au = make_uint4(packbf2(v0.x, v0.y), packbf2(v0.z, v0.w),
                              packbf2(v1.x, v1.y), packbf2(v1.z, v1.w));
        short8 a = *(short8*)&au;
        #pragma unroll
        for (int ct = 0; ct < 8; ++ct) {
            uint4 bu = *(const uint4*)(wbf + (size_t)(ct * 16 + l16) * 64 + kt * 16 + kg * 4);
            short8 b = *(short8*)&bu;
            acc[ct] = __builtin_amdgcn_mfma_f32_16x16x32_bf16(a, b, acc[ct], 0, 0, 0);
        }
    }

    #pragma unroll
    for (int ct = 0; ct < 8; ++ct)
        #pragma unroll
        for (int r = 0; r < 4; ++r)
            cst[(wv * 16 + kg * 4 + r) * 129 + ct * 16 + l16] = acc[ct][r];
    __syncthreads();

    int row = t & 63, q = t >> 6;
    int grow = bx * 64 + row;
    if (grow < M) {
        const float* src = cst + row * 129 + q * 32;
        unsigned pk[16];
        #pragma unroll
        for (int i = 0; i < 16; ++i) pk[i] = packbf2(src[2 * i], src[2 * i + 1]);
        uint4* dst = (uint4*)(zb + (size_t)grow * 64 + q * 16);
        #pragma unroll
        for (int qq = 0; qq < 4; ++qq)
            dst[qq] = make_uint4(pk[4 * qq], pk[4 * qq + 1], pk[4 * qq + 2], pk[4 * qq + 3]);
    }
}

__global__ __launch_bounds__(256) void pg_k(
        const int* __restrict__ src1, const int* __restrict__ dst1,
        const int* __restrict__ src2, const int* __restrict__ dst2,
        unsigned* __restrict__ slab1, unsigned* __restrict__ slab2,
        int* __restrict__ gcur1, int* __restrict__ gcur2, int E, int NB,
        const float* __restrict__ x, const unsigned* __restrict__ wbf1,
        unsigned* __restrict__ zb, int M) {
    __shared__ __align__(16) char smem[36864];
    int bx = blockIdx.x;
    if (bx < 2 * NB)
        partition_body(smem, bx, src1, dst1, src2, dst2,
                       slab1, slab2, gcur1, gcur2, E, NB);
    else
        gemm1_body(smem, bx - 2 * NB, x, wbf1, zb, M);
}

// Phase B: per (bucket, dir): counting-sort slab by node in LDS, emit exact CSR.
__global__ __launch_bounds__(256) void csr_k(
        const unsigned* __restrict__ slab1, const unsigned* __restrict__ slab2,
        const int* __restrict__ gcur1, const int* __restrict__ gcur2,
        unsigned short* __restrict__ list1, unsigned short* __restrict__ list2,
        unsigned* __restrict__ goff1, unsigned* __restrict__ goff2,
        unsigned short* __restrict__ gcnt1, unsigned short* __restrict__ gcnt2,
        int N) {
    __shared__ unsigned short srt[SLAB_CAP];
    __shared__ int cnt[256], loff[256], cur[256];

    int t = threadIdx.x;
    int dir = (blockIdx.x >= C_BKT) ? 1 : 0;
    int b = dir ? (blockIdx.x - C_BKT) : blockIdx.x;
    const unsigned* sl = (dir ? slab2 : slab1) + (size_t)b * SLAB_CAP;
    unsigned short* lst = dir ? list2 : list1;
    unsigned* goffN = dir ? goff2 : goff1;
    unsigned short* gcntN = dir ? gcnt2 : gcnt1;
    int nv = (dir ? gcur2 : gcur1)[b] - b * SLAB_CAP;
    if (nv > SLAB_CAP) nv = SLAB_CAP;

    cnt[t] = 0;
    __syncthreads();
    for (int j = t; j < nv; j += 256) atomicAdd(&cnt[sl[j] >> 16], 1);
    __syncthreads();

    int c = cnt[t];
    for (int d = 1; d < 256; d <<= 1) {
        int v = (t >= d) ? cnt[t - d] : 0;
        __syncthreads();
        cnt[t] += v;
        __syncthreads();
    }
    loff[t] = cnt[t] - c;
    cur[t] = 0;
    int node = b * 256 + t;
    if (node < N) {
        goffN[node] = (unsigned)(b * SLAB_CAP + loff[t]);
        gcntN[node] = (unsigned short)c;
    }
    __syncthreads();

    for (int j = t; j < nv; j += 256) {
        unsigned v = sl[j];
        int n = v >> 16;
        int r = atomicAdd(&cur[n], 1);
        srt[loff[n] + r] = (unsigned short)(v & 0xffffu);
    }
    __syncthreads();
    for (int j = t; j < nv; j += 256)
        lst[(size_t)b * SLAB_CAP + j] = srt[j];
}

// GEMM2: A = s (bf16), out = relu(A@W^T + b2) f32. Direct stores.
__global__ __launch_bounds__(256) void gemm2_mfma_k(
        const unsigned* __restrict__ sB, const unsigned* __restrict__ wbf,
        const float* __restrict__ bias, float* __restrict__ O, int M) {
    int t = threadIdx.x;
    int lane = t & 63, wv = t >> 6;
    int l16 = lane & 15, kg = lane >> 4;
    int rowBase = blockIdx.x * 64 + wv * 16;
    int ar = rowBase + l16; if (ar >= M) ar = M - 1;

    f32x4 acc[8];
    #pragma unroll
    for (int ct = 0; ct < 8; ++ct) acc[ct] = (f32x4){0.f, 0.f, 0.f, 0.f};

    #pragma unroll
    for (int kt = 0; kt < 4; ++kt) {
        uint4 au = *(const uint4*)(sB + (size_t)ar * 64 + kt * 16 + kg * 4);
        short8 a = *(short8*)&au;
        #pragma unroll
        for (int ct = 0; ct < 8; ++ct) {
            uint4 bu = *(const uint4*)(wbf + (size_t)(ct * 16 + l16) * 64 + kt * 16 + kg * 4);
            short8 b = *(short8*)&bu;
            acc[ct] = __builtin_amdgcn_mfma_f32_16x16x32_bf16(a, b, acc[ct], 0, 0, 0);
        }
    }

    #pragma unroll
    for (int ct = 0; ct < 8; ++ct) {
        int col = ct * 16 + l16;
        float bv = bias[col];
        #pragma unroll
        for (int r = 0; r < 4; ++r) {
            int grow = rowBase + kg * 4 + r;
            if (grow < M)
                O[(size_t)grow * 128 + col] = fmaxf(acc[ct][r] + bv, 0.f);
        }
    }
}

// ---------------- gather (r9 structure, verbatim: measured 55us) ----------
template<int B>
__device__ inline void batchsum(const unsigned short* __restrict__ lst, int o,
                                const unsigned* __restrict__ zb, int lane,
                                float& ax, float& ay) {
    unsigned idx[B], pv[B];
    #pragma unroll
    for (int u = 0; u < B; ++u) idx[u] = lst[o + u];
    #pragma unroll
    for (int u = 0; u < B; ++u) pv[u] = zb[(size_t)idx[u] * 64 + lane];
    float sx = 0.f, sy = 0.f;
    #pragma unroll
    for (int u = 0; u < B; ++u) { sx += BFLO(pv[u]); sy += BFHI(pv[u]); }
    ax += sx; ay += sy;
}

// One node per 64-lane wave; bf16 z rows (uint = 2 elems/lane).
// 16/8/4-deep pipelined loads; f32 accumulate; bf16-packed s output.
__global__ __launch_bounds__(256) void gather_fuse_k(
        const unsigned* __restrict__ zb,
        const unsigned* __restrict__ goff1, const unsigned short* __restrict__ gcnt1,
        const unsigned short* __restrict__ list1,
        const unsigned* __restrict__ goff2, const unsigned short* __restrict__ gcnt2,
        const unsigned short* __restrict__ list2,
        const float* __restrict__ b1, unsigned* __restrict__ sOut, int N) {
    int g = __builtin_amdgcn_readfirstlane(blockIdx.x * 4 + (threadIdx.x >> 6));
    if (g >= N) return;
    int lane = threadIdx.x & 63;

    float a1x = 0.f, a1y = 0.f, a2x = 0.f, a2y = 0.f;

    {
        int o = (int)goff1[g], c = (int)gcnt1[g], i = 0;
        for (; i + 16 <= c; i += 16) batchsum<16>(list1, o + i, zb, lane, a1x, a1y);
        if (i + 8 <= c) { batchsum<8>(list1, o + i, zb, lane, a1x, a1y); i += 8; }
        if (i + 4 <= c) { batchsum<4>(list1, o + i, zb, lane, a1x, a1y); i += 4; }
        for (; i < c; ++i) {
            unsigned p = zb[(size_t)list1[o + i] * 64 + lane];
            a1x += BFLO(p); a1y += BFHI(p);
        }
    }
    {
        int o = (int)goff2[g], c = (int)gcnt2[g], i = 0;
        for (; i + 16 <= c; i += 16) batchsum<16>(list2, o + i, zb, lane, a2x, a2y);
        if (i + 8 <= c) { batchsum<8>(list2, o + i, zb, lane, a2x, a2y); i += 8; }
        if (i + 4 <= c) { batchsum<4>(list2, o + i, zb, lane, a2x, a2y); i += 4; }
        for (; i < c; ++i) {
            unsigned p = zb[(size_t)list2[o + i] * 64 + lane];
            a2x += BFLO(p); a2y += BFHI(p);
        }
    }

    unsigned pz = zb[(size_t)g * 64 + lane];
    float2 bb = ((const float2*)b1)[lane];
    float bx = BFLO(pz) + bb.x, by = BFHI(pz) + bb.y;
    float ox = 0.5f * (fmaxf(bx + a1x, 0.f) + fmaxf(bx + a2x, 0.f));
    float oy = 0.5f * (fmaxf(by + a1y, 0.f) + fmaxf(by + a2y, 0.f));
    sOut[(size_t)g * 64 + lane] = packbf2(ox, oy);
}

extern "C" void kernel_launch(void* const* d_in, const int* in_sizes, int n_in,
                              void* d_out, int out_size, void* d_ws, size_t ws_size,
                              hipStream_t stream) {
    const float* x   = (const float*)d_in[0];
    const int*   ei  = (const int*)d_in[1];
    const int*   rei = (const int*)d_in[2];
    const float* w1  = (const float*)d_in[3];
    const float* b1  = (const float*)d_in[4];
    const float* w2  = (const float*)d_in[5];
    const float* b2  = (const float*)d_in[6];
    float* out = (float*)d_out;

    const int N = in_sizes[0] / 128;      // 50000
    const int E = in_sizes[1] / 2;        // 800000
    const size_t ND = (size_t)N * 128;
    const size_t SL = (size_t)C_BKT * SLAB_CAP;   // 903168

    // ws layout (~38 MB)
    unsigned* zb    = (unsigned*)d_ws;            // N*64  (bf16 z, 12.8 MB)
    unsigned* sb    = zb + ND / 2;                // N*64  (bf16 s, 12.8 MB)
    unsigned* wbf1  = sb + ND / 2;                // 8192  (bf16 w1, 32 KB)
    unsigned* wbf2  = wbf1 + 8192;                // 8192
    unsigned* slab1 = wbf2 + 8192;                // SL
    unsigned* slab2 = slab1 + SL;                 // SL
    unsigned* goff1 = slab2 + SL;                 // N
    unsigned* goff2 = goff1 + N;                  // N
    int*      gcur1 = (int*)(goff2 + N);          // C_BKT
    int*      gcur2 = gcur1 + C_BKT;              // C_BKT
    unsigned short* gcnt1 = (unsigned short*)(gcur2 + C_BKT);  // N
    unsigned short* gcnt2 = gcnt1 + N;            // N
    unsigned short* list1 = gcnt2 + N;            // SL
    unsigned short* list2 = list1 + SL;           // SL

    const int* src1 = ei,  *dst1 = ei + E;
    const int* src2 = rei, *dst2 = rei + E;

    // 1. weight bf16 convert (8192 pairs = 32 blocks) + slab cursor init
    prep_k<<<33, 256, 0, stream>>>(w1, w2, wbf1, wbf2, gcur1, gcur2);

    // 2. fused: partition (392 blocks) || gemm1 (782 blocks)
    int NB = (E + CHUNK - 1) / CHUNK;   // 196
    int gB = (N + 63) / 64;             // 782
    pg_k<<<2 * NB + gB, 256, 0, stream>>>(src1, dst1, src2, dst2,
                                          slab1, slab2, gcur1, gcur2, E, NB,
                                          x, wbf1, zb, N);

    // 3. in-LDS counting sort -> exact CSR
    csr_k<<<2 * C_BKT, 256, 0, stream>>>(slab1, slab2, gcur1, gcur2,
                                         list1, list2, goff1, goff2,
                                         gcnt1, gcnt2, N);

    // 4. fused gather + activation -> s (bf16); 1 node per wave (r9)
    gather_fuse_k<<<(N + 3) / 4, 256, 0, stream>>>(zb, goff1, gcnt1, list1,
                                                   goff2, gcnt2, list2, b1, sb, N);

    // 5. out = relu(s @ w2^T + b2)  (MFMA, f32 out)
    gemm2_mfma_k<<<gB, 256, 0, stream>>>(sb, wbf2, b2, out, N);
}